// Round 1
// baseline (454.428 us; speedup 1.0000x reference)
//
#include <hip/hip_runtime.h>
#include <hip/hip_bf16.h>

#define EE 768
#define HH 4
#define KK 36
#define BSN 2048

typedef __attribute__((ext_vector_type(8))) short short8;
typedef __attribute__((ext_vector_type(4))) short short4v;
typedef __attribute__((ext_vector_type(4))) float float4v;

__device__ inline short f2bf(float x){
  return __builtin_bit_cast(short, __float2bfloat16(x));
}
__device__ inline float bf2f(short s){
  return __bfloat162float(__builtin_bit_cast(__hip_bfloat16, s));
}
__device__ inline float gelu_tanh(float x){
  // jax.nn.gelu default (approximate=True)
  float t = tanhf(0.79788456080286536f * (x + 0.044715f * x * x * x));
  return 0.5f * x * (1.0f + t);
}

// ---------------------------------------------------------------------------
// v[h][e] = g[h][e] * sum_f W1[h][e][f] * W2y[h][f]    (one wave per (h,e))
// also initializes b1p = b1 (first 12 blocks' worth of threads)
// ---------------------------------------------------------------------------
__global__ __launch_bounds__(256) void k_v(const float* __restrict__ W1,
                                           const float* __restrict__ W2y,
                                           const float* __restrict__ g,
                                           const float* __restrict__ b1,
                                           float* __restrict__ v,
                                           float* __restrict__ b1p){
  const int wid  = blockIdx.x * 4 + (threadIdx.x >> 6);
  const int lane = threadIdx.x & 63;
  const int h = wid / EE, e = wid % EE;
  const float* W  = W1 + ((size_t)h * EE + e) * EE;
  const float* wy = W2y + h * EE;
  float acc = 0.f;
  #pragma unroll
  for (int j = 0; j < 12; ++j){
    int f = lane + 64 * j;
    acc += W[f] * wy[f];
  }
  #pragma unroll
  for (int off = 32; off; off >>= 1) acc += __shfl_xor(acc, off);
  if (lane == 0) v[h * EE + e] = g[h * EE + e] * acc;

  int idx = blockIdx.x * 256 + threadIdx.x;
  if (idx < HH * EE) b1p[idx] = b1[idx];
}

// ---------------------------------------------------------------------------
// b1p[h][f] += sum_e beta[h][e] * W1[h][e][f]   (partial e-chunks + atomics)
// grid: 32 blocks = 4 h * 8 e-chunks of 96
// ---------------------------------------------------------------------------
__global__ __launch_bounds__(256) void k_b1p_acc(const float* __restrict__ W1,
                                                 const float* __restrict__ beta,
                                                 float* __restrict__ b1p){
  const int h   = blockIdx.x >> 3;
  const int ec0 = (blockIdx.x & 7) * 96;
  const float* W  = W1 + (size_t)h * EE * EE;
  const float* bt = beta + h * EE;
  const int f = threadIdx.x;
  float a0 = 0.f, a1 = 0.f, a2 = 0.f;
  for (int e = ec0; e < ec0 + 96; ++e){
    float be = bt[e];
    const float* row = W + (size_t)e * EE;
    a0 += be * row[f];
    a1 += be * row[f + 256];
    a2 += be * row[f + 512];
  }
  atomicAdd(&b1p[h * EE + f],       a0);
  atomicAdd(&b1p[h * EE + f + 256], a1);
  atomicAdd(&b1p[h * EE + f + 512], a2);
}

// ---------------------------------------------------------------------------
// W1t[h][f][e] = bf16( g[h][e] * W1[h][e][f] )   (transposed, bf16)
// grid (24 e-tiles, 24 f-tiles, 4 h), 256 threads
// ---------------------------------------------------------------------------
__global__ __launch_bounds__(256) void k_tW1(const float* __restrict__ W1,
                                             const float* __restrict__ g,
                                             short* __restrict__ W1t){
  __shared__ float tile[32][33];
  const int h  = blockIdx.z;
  const int e0 = blockIdx.x * 32, f0 = blockIdx.y * 32;
  const int tx = threadIdx.x & 31, ty = threadIdx.x >> 5;
  const float* W = W1 + (size_t)h * EE * EE;
  #pragma unroll
  for (int i = 0; i < 4; ++i){
    int e = e0 + ty + 8 * i;
    tile[ty + 8 * i][tx] = W[(size_t)e * EE + f0 + tx] * g[h * EE + e];
  }
  __syncthreads();
  #pragma unroll
  for (int i = 0; i < 4; ++i){
    int f = f0 + ty + 8 * i;
    W1t[((size_t)h * EE + f) * EE + e0 + tx] = f2bf(tile[tx][ty + 8 * i]);
  }
}

// ---------------------------------------------------------------------------
// Wmt[f][c] = bf16( Wm[c][f] )   c in [0,3072), f in [0,768)
// grid (96 c-tiles, 24 f-tiles)
// ---------------------------------------------------------------------------
__global__ __launch_bounds__(256) void k_tWm(const float* __restrict__ Wm,
                                             short* __restrict__ Wmt){
  __shared__ float tile[32][33];
  const int c0 = blockIdx.x * 32, f0 = blockIdx.y * 32;
  const int tx = threadIdx.x & 31, ty = threadIdx.x >> 5;
  #pragma unroll
  for (int i = 0; i < 4; ++i){
    tile[ty + 8 * i][tx] = Wm[(size_t)(c0 + ty + 8 * i) * EE + f0 + tx];
  }
  __syncthreads();
  #pragma unroll
  for (int i = 0; i < 4; ++i){
    Wmt[(size_t)(f0 + ty + 8 * i) * (HH * EE) + c0 + tx] = f2bf(tile[tx][ty + 8 * i]);
  }
}

// ---------------------------------------------------------------------------
// Fused y pass: per row n (block): LN0(y[n,k,:]) -> yn (bf16 LDS),
// logits[k][h] = yn . v_h, softmax over k, p_y[h][n][e] = sum_k prob*yn.
// x_ / W2x / b2 terms cancel in the softmax (constant in k).
// ---------------------------------------------------------------------------
__global__ __launch_bounds__(256) void k_pass_y(const float* __restrict__ y,
                                                const float* __restrict__ v,
                                                short* __restrict__ p_y){
  __shared__ short yn_s[KK][EE];          // 55296 B
  __shared__ float logits_s[KK][HH];
  __shared__ float prob_s[KK][HH];
  const int n = blockIdx.x;
  const int wave = threadIdx.x >> 6, lane = threadIdx.x & 63;

  float4v vreg[HH][3];
  #pragma unroll
  for (int h = 0; h < HH; ++h)
    #pragma unroll
    for (int j = 0; j < 3; ++j)
      vreg[h][j] = *(const float4v*)(v + h * EE + 4 * lane + 256 * j);

  for (int k = wave; k < KK; k += 4){
    const float* yrow = y + ((size_t)n * KK + k) * EE;
    float4v yv[3];
    float s = 0.f, s2 = 0.f;
    #pragma unroll
    for (int j = 0; j < 3; ++j){
      yv[j] = *(const float4v*)(yrow + 4 * lane + 256 * j);
      #pragma unroll
      for (int c = 0; c < 4; ++c){ float t = yv[j][c]; s += t; s2 += t * t; }
    }
    #pragma unroll
    for (int off = 32; off; off >>= 1){
      s  += __shfl_xor(s, off);
      s2 += __shfl_xor(s2, off);
    }
    const float mu = s * (1.f / EE);
    const float rs = rsqrtf(s2 * (1.f / EE) - mu * mu + 1e-5f);
    float d0 = 0.f, d1 = 0.f, d2 = 0.f, d3 = 0.f;
    #pragma unroll
    for (int j = 0; j < 3; ++j){
      short4v pk;
      #pragma unroll
      for (int c = 0; c < 4; ++c){
        float t = (yv[j][c] - mu) * rs;
        pk[c] = f2bf(t);
        d0 += t * vreg[0][j][c];
        d1 += t * vreg[1][j][c];
        d2 += t * vreg[2][j][c];
        d3 += t * vreg[3][j][c];
      }
      *(short4v*)(&yn_s[k][4 * lane + 256 * j]) = pk;
    }
    #pragma unroll
    for (int off = 32; off; off >>= 1){
      d0 += __shfl_xor(d0, off);
      d1 += __shfl_xor(d1, off);
      d2 += __shfl_xor(d2, off);
      d3 += __shfl_xor(d3, off);
    }
    if (lane == 0){
      logits_s[k][0] = d0; logits_s[k][1] = d1;
      logits_s[k][2] = d2; logits_s[k][3] = d3;
    }
  }
  __syncthreads();
  {
    const int h = wave;          // exactly 4 waves, 4 heads
    float l = (lane < KK) ? logits_s[lane][h] : -1e30f;
    float mx = l;
    #pragma unroll
    for (int off = 32; off; off >>= 1) mx = fmaxf(mx, __shfl_xor(mx, off));
    float ex = (lane < KK) ? __expf(l - mx) : 0.f;
    float sm = ex;
    #pragma unroll
    for (int off = 32; off; off >>= 1) sm += __shfl_xor(sm, off);
    if (lane < KK) prob_s[lane][h] = ex / sm;
  }
  __syncthreads();
  if (threadIdx.x < 192){
    const int e = 4 * threadIdx.x;
    float a[HH][4];
    #pragma unroll
    for (int h = 0; h < HH; ++h)
      #pragma unroll
      for (int c = 0; c < 4; ++c) a[h][c] = 0.f;
    for (int k = 0; k < KK; ++k){
      short4v yp = *(const short4v*)(&yn_s[k][e]);
      float p0 = prob_s[k][0], p1 = prob_s[k][1], p2 = prob_s[k][2], p3 = prob_s[k][3];
      #pragma unroll
      for (int c = 0; c < 4; ++c){
        float t = bf2f(yp[c]);
        a[0][c] += p0 * t; a[1][c] += p1 * t; a[2][c] += p2 * t; a[3][c] += p3 * t;
      }
    }
    #pragma unroll
    for (int h = 0; h < HH; ++h){
      short4v pk;
      #pragma unroll
      for (int c = 0; c < 4; ++c) pk[c] = f2bf(a[h][c]);
      *(short4v*)(p_y + ((size_t)h * BSN + n) * EE + e) = pk;
    }
  }
}

// ---------------------------------------------------------------------------
// 64x64-tile bf16 MFMA GEMM, C = A @ Bt^T with fused epilogue.
// A: [M][Kdim] bf16 row-major. Bt: [N][Kdim] bf16 (i.e. B transposed).
// MODE 0: cat[m][768*z + f] = bf16( gelu(x[m][f] + acc + addv[768z+f]) )
// MODE 1: out[m][f]         = x[m][f] + gelu(acc + addv[f])
// grid (M/64, N/64, Z)
// ---------------------------------------------------------------------------
template<int MODE>
__global__ __launch_bounds__(256) void k_gemm(const short* __restrict__ A,
                                              const short* __restrict__ Bt,
                                              const float* __restrict__ addv,
                                              const float* __restrict__ x,
                                              void* __restrict__ out,
                                              int Kdim, size_t strideA, size_t strideB){
  __shared__ short As[64][72];
  __shared__ short Bs[64][72];
  const int z = blockIdx.z;
  const short* Ah = A + strideA * z;
  const short* Bh = Bt + strideB * z;
  const float* addh = addv + (size_t)768 * z;

  const int tid = threadIdx.x;
  const int wave = tid >> 6, lane = tid & 63;
  const int quad = lane >> 4, l16 = lane & 15;
  const int m0 = blockIdx.x * 64, n0 = blockIdx.y * 64;
  const int r = tid >> 3, c8 = (tid & 7) * 8;

  float4v acc[4];
  #pragma unroll
  for (int t = 0; t < 4; ++t) acc[t] = (float4v){0.f, 0.f, 0.f, 0.f};

  const short* Ap0 = Ah + (size_t)(m0 + r) * Kdim + c8;
  const short* Ap1 = Ah + (size_t)(m0 + r + 32) * Kdim + c8;
  const short* Bp0 = Bh + (size_t)(n0 + r) * Kdim + c8;
  const short* Bp1 = Bh + (size_t)(n0 + r + 32) * Kdim + c8;

  for (int k0 = 0; k0 < Kdim; k0 += 64){
    short8 a0 = *(const short8*)(Ap0 + k0);
    short8 a1 = *(const short8*)(Ap1 + k0);
    short8 b0 = *(const short8*)(Bp0 + k0);
    short8 b1 = *(const short8*)(Bp1 + k0);
    __syncthreads();
    *(short8*)(&As[r][c8])      = a0;
    *(short8*)(&As[r + 32][c8]) = a1;
    *(short8*)(&Bs[r][c8])      = b0;
    *(short8*)(&Bs[r + 32][c8]) = b1;
    __syncthreads();
    #pragma unroll
    for (int kk = 0; kk < 64; kk += 32){
      short8 bf = *(const short8*)(&Bs[16 * wave + l16][kk + quad * 8]);
      #pragma unroll
      for (int t = 0; t < 4; ++t){
        short8 af = *(const short8*)(&As[16 * t + l16][kk + quad * 8]);
        acc[t] = __builtin_amdgcn_mfma_f32_16x16x32_bf16(af, bf, acc[t], 0, 0, 0);
      }
    }
  }

  const int f = n0 + 16 * wave + l16;       // local col in [0,768)
  const float add = addh[f];
  #pragma unroll
  for (int t = 0; t < 4; ++t){
    #pragma unroll
    for (int rr = 0; rr < 4; ++rr){
      const int m = m0 + 16 * t + quad * 4 + rr;
      const float val = acc[t][rr] + add;
      const float xf = x[(size_t)m * EE + f];
      if (MODE == 0){
        ((short*)out)[(size_t)m * (HH * EE) + 768 * z + f] = f2bf(gelu_tanh(xf + val));
      } else {
        ((float*)out)[(size_t)m * EE + f] = xf + gelu_tanh(val);
      }
    }
  }
}

// ---------------------------------------------------------------------------
extern "C" void kernel_launch(void* const* d_in, const int* in_sizes, int n_in,
                              void* d_out, int out_size, void* d_ws, size_t ws_size,
                              hipStream_t stream){
  const float* x    = (const float*)d_in[0];
  const float* y    = (const float*)d_in[1];
  const float* g    = (const float*)d_in[2];
  const float* beta = (const float*)d_in[3];
  const float* W1   = (const float*)d_in[4];
  const float* b1   = (const float*)d_in[5];
  const float* W2y  = (const float*)d_in[7];   // W2x, b2 cancel in softmax
  const float* Wm   = (const float*)d_in[9];
  const float* bm   = (const float*)d_in[10];

  char* ws = (char*)d_ws;
  float* v    = (float*)(ws + 0);              // 4*768 f32
  float* b1p  = (float*)(ws + 12288);          // 4*768 f32
  short* W1t  = (short*)(ws + 24576);          // 4*768*768 bf16 (transposed)
  short* Wmt  = (short*)(ws + 4743168);        // 768*3072 bf16 (transposed)
  short* p_y  = (short*)(ws + 9461760);        // 4*2048*768 bf16
  short* catb = (short*)(ws + 22044672);       // 2048*3072 bf16
  float* out  = (float*)d_out;

  k_v<<<dim3(768), dim3(256), 0, stream>>>(W1, W2y, g, b1, v, b1p);
  k_b1p_acc<<<dim3(32), dim3(256), 0, stream>>>(W1, beta, b1p);
  k_tW1<<<dim3(24, 24, 4), dim3(256), 0, stream>>>(W1, g, W1t);
  k_tWm<<<dim3(96, 24), dim3(256), 0, stream>>>(Wm, Wmt);
  k_pass_y<<<dim3(2048), dim3(256), 0, stream>>>(y, v, p_y);
  k_gemm<0><<<dim3(32, 12, 4), dim3(256), 0, stream>>>(
      p_y, W1t, b1p, x, (void*)catb, 768, (size_t)2048 * 768, (size_t)768 * 768);
  k_gemm<1><<<dim3(32, 12, 1), dim3(256), 0, stream>>>(
      catb, Wmt, bm, x, (void*)out, 3072, (size_t)0, (size_t)0);
}

// Round 2
// 444.191 us; speedup vs baseline: 1.0230x; 1.0230x over previous
//
#include <hip/hip_runtime.h>
#include <hip/hip_bf16.h>

#define EE 768
#define HH 4
#define KK 36
#define BSN 2048

typedef __attribute__((ext_vector_type(8))) short short8;
typedef __attribute__((ext_vector_type(4))) short short4v;
typedef __attribute__((ext_vector_type(4))) float float4v;

__device__ inline short f2bf(float x){
  return __builtin_bit_cast(short, __float2bfloat16(x));
}
__device__ inline float bf2f(short s){
  return __bfloat162float(__builtin_bit_cast(__hip_bfloat16, s));
}
__device__ inline float gelu_tanh(float x){
  // jax.nn.gelu default (approximate=True)
  float t = tanhf(0.79788456080286536f * (x + 0.044715f * x * x * x));
  return 0.5f * x * (1.0f + t);
}

// ---------------------------------------------------------------------------
// v[h][e] = g[h][e] * sum_f W1[h][e][f] * W2y[h][f]    (one wave per (h,e))
// also initializes b1p = b1 (first 12 blocks' worth of threads)
// ---------------------------------------------------------------------------
__global__ __launch_bounds__(256) void k_v(const float* __restrict__ W1,
                                           const float* __restrict__ W2y,
                                           const float* __restrict__ g,
                                           const float* __restrict__ b1,
                                           float* __restrict__ v,
                                           float* __restrict__ b1p){
  const int wid  = blockIdx.x * 4 + (threadIdx.x >> 6);
  const int lane = threadIdx.x & 63;
  const int h = wid / EE, e = wid % EE;
  const float* W  = W1 + ((size_t)h * EE + e) * EE;
  const float* wy = W2y + h * EE;
  float acc = 0.f;
  #pragma unroll
  for (int j = 0; j < 12; ++j){
    int f = lane + 64 * j;
    acc += W[f] * wy[f];
  }
  #pragma unroll
  for (int off = 32; off; off >>= 1) acc += __shfl_xor(acc, off);
  if (lane == 0) v[h * EE + e] = g[h * EE + e] * acc;

  int idx = blockIdx.x * 256 + threadIdx.x;
  if (idx < HH * EE) b1p[idx] = b1[idx];
}

// ---------------------------------------------------------------------------
// b1p[h][f] += sum_e beta[h][e] * W1[h][e][f]   (partial e-chunks + atomics)
// grid: 256 blocks = 4 h * 64 e-chunks of 12
// ---------------------------------------------------------------------------
__global__ __launch_bounds__(256) void k_b1p_acc(const float* __restrict__ W1,
                                                 const float* __restrict__ beta,
                                                 float* __restrict__ b1p){
  const int h   = blockIdx.x >> 6;
  const int ec0 = (blockIdx.x & 63) * 12;
  const float* W  = W1 + (size_t)h * EE * EE;
  const float* bt = beta + h * EE;
  const int f = threadIdx.x;
  float a0 = 0.f, a1 = 0.f, a2 = 0.f;
  #pragma unroll
  for (int e = ec0; e < ec0 + 12; ++e){
    float be = bt[e];
    const float* row = W + (size_t)e * EE;
    a0 += be * row[f];
    a1 += be * row[f + 256];
    a2 += be * row[f + 512];
  }
  atomicAdd(&b1p[h * EE + f],       a0);
  atomicAdd(&b1p[h * EE + f + 256], a1);
  atomicAdd(&b1p[h * EE + f + 512], a2);
}

// ---------------------------------------------------------------------------
// W1t[h][f][e] = bf16( g[h][e] * W1[h][e][f] )   (transposed, bf16)
// grid (24 e-tiles, 24 f-tiles, 4 h), 256 threads
// ---------------------------------------------------------------------------
__global__ __launch_bounds__(256) void k_tW1(const float* __restrict__ W1,
                                             const float* __restrict__ g,
                                             short* __restrict__ W1t){
  __shared__ float tile[32][33];
  const int h  = blockIdx.z;
  const int e0 = blockIdx.x * 32, f0 = blockIdx.y * 32;
  const int tx = threadIdx.x & 31, ty = threadIdx.x >> 5;
  const float* W = W1 + (size_t)h * EE * EE;
  #pragma unroll
  for (int i = 0; i < 4; ++i){
    int e = e0 + ty + 8 * i;
    tile[ty + 8 * i][tx] = W[(size_t)e * EE + f0 + tx] * g[h * EE + e];
  }
  __syncthreads();
  #pragma unroll
  for (int i = 0; i < 4; ++i){
    int f = f0 + ty + 8 * i;
    W1t[((size_t)h * EE + f) * EE + e0 + tx] = f2bf(tile[tx][ty + 8 * i]);
  }
}

// ---------------------------------------------------------------------------
// Wmt[f][c] = bf16( Wm[c][f] )   c in [0,3072), f in [0,768)
// grid (96 c-tiles, 24 f-tiles)
// ---------------------------------------------------------------------------
__global__ __launch_bounds__(256) void k_tWm(const float* __restrict__ Wm,
                                             short* __restrict__ Wmt){
  __shared__ float tile[32][33];
  const int c0 = blockIdx.x * 32, f0 = blockIdx.y * 32;
  const int tx = threadIdx.x & 31, ty = threadIdx.x >> 5;
  #pragma unroll
  for (int i = 0; i < 4; ++i){
    tile[ty + 8 * i][tx] = Wm[(size_t)(c0 + ty + 8 * i) * EE + f0 + tx];
  }
  __syncthreads();
  #pragma unroll
  for (int i = 0; i < 4; ++i){
    Wmt[(size_t)(f0 + ty + 8 * i) * (HH * EE) + c0 + tx] = f2bf(tile[tx][ty + 8 * i]);
  }
}

// ---------------------------------------------------------------------------
// Fused y pass: per row n (block): LN0(y[n,k,:]) -> yn (bf16 LDS),
// logits[k][h] = yn . v_h, softmax over k, p_y[h][n][e] = sum_k prob*yn.
// x_ / W2x / b2 terms cancel in the softmax (constant in k).
// Latency fix: each wave issues ALL 27 global_load_dwordx4 (9 k-rows) before
// any dependent compute -> ~7 KB in flight per wave (Little's law needs ~9
// KB/CU at 900cyc to hit 10 B/cyc/CU; 8 waves/CU x 432B = 55 KB).
// ---------------------------------------------------------------------------
__global__ __launch_bounds__(256, 2) void k_pass_y(const float* __restrict__ y,
                                                   const float* __restrict__ v,
                                                   short* __restrict__ p_y){
  __shared__ short yn_s[KK][EE];          // 55296 B
  __shared__ float logits_s[KK][HH];
  __shared__ float prob_s[KK][HH];
  const int n = blockIdx.x;
  const int wave = threadIdx.x >> 6, lane = threadIdx.x & 63;

  // Issue all 9 rows' loads up front (27 independent dwordx4 per lane).
  float4v yv[9][3];
  #pragma unroll
  for (int i = 0; i < 9; ++i){
    const int k = wave + 4 * i;
    const float* yrow = y + ((size_t)n * KK + k) * EE;
    #pragma unroll
    for (int j = 0; j < 3; ++j)
      yv[i][j] = *(const float4v*)(yrow + 4 * lane + 256 * j);
  }

  float4v vreg[HH][3];
  #pragma unroll
  for (int h = 0; h < HH; ++h)
    #pragma unroll
    for (int j = 0; j < 3; ++j)
      vreg[h][j] = *(const float4v*)(v + h * EE + 4 * lane + 256 * j);

  #pragma unroll
  for (int i = 0; i < 9; ++i){
    const int k = wave + 4 * i;
    float s = 0.f, s2 = 0.f;
    #pragma unroll
    for (int j = 0; j < 3; ++j)
      #pragma unroll
      for (int c = 0; c < 4; ++c){ float t = yv[i][j][c]; s += t; s2 += t * t; }
    #pragma unroll
    for (int off = 32; off; off >>= 1){
      s  += __shfl_xor(s, off);
      s2 += __shfl_xor(s2, off);
    }
    const float mu = s * (1.f / EE);
    const float rs = rsqrtf(s2 * (1.f / EE) - mu * mu + 1e-5f);
    float d0 = 0.f, d1 = 0.f, d2 = 0.f, d3 = 0.f;
    #pragma unroll
    for (int j = 0; j < 3; ++j){
      short4v pk;
      #pragma unroll
      for (int c = 0; c < 4; ++c){
        float t = (yv[i][j][c] - mu) * rs;
        pk[c] = f2bf(t);
        d0 += t * vreg[0][j][c];
        d1 += t * vreg[1][j][c];
        d2 += t * vreg[2][j][c];
        d3 += t * vreg[3][j][c];
      }
      *(short4v*)(&yn_s[k][4 * lane + 256 * j]) = pk;
    }
    #pragma unroll
    for (int off = 32; off; off >>= 1){
      d0 += __shfl_xor(d0, off);
      d1 += __shfl_xor(d1, off);
      d2 += __shfl_xor(d2, off);
      d3 += __shfl_xor(d3, off);
    }
    if (lane == 0){
      logits_s[k][0] = d0; logits_s[k][1] = d1;
      logits_s[k][2] = d2; logits_s[k][3] = d3;
    }
  }
  __syncthreads();
  {
    const int h = wave;          // exactly 4 waves, 4 heads
    float l = (lane < KK) ? logits_s[lane][h] : -1e30f;
    float mx = l;
    #pragma unroll
    for (int off = 32; off; off >>= 1) mx = fmaxf(mx, __shfl_xor(mx, off));
    float ex = (lane < KK) ? __expf(l - mx) : 0.f;
    float sm = ex;
    #pragma unroll
    for (int off = 32; off; off >>= 1) sm += __shfl_xor(sm, off);
    if (lane < KK) prob_s[lane][h] = ex / sm;
  }
  __syncthreads();
  if (threadIdx.x < 192){
    const int e = 4 * threadIdx.x;
    float a[HH][4];
    #pragma unroll
    for (int h = 0; h < HH; ++h)
      #pragma unroll
      for (int c = 0; c < 4; ++c) a[h][c] = 0.f;
    #pragma unroll 4
    for (int k = 0; k < KK; ++k){
      short4v yp = *(const short4v*)(&yn_s[k][e]);
      float p0 = prob_s[k][0], p1 = prob_s[k][1], p2 = prob_s[k][2], p3 = prob_s[k][3];
      #pragma unroll
      for (int c = 0; c < 4; ++c){
        float t = bf2f(yp[c]);
        a[0][c] += p0 * t; a[1][c] += p1 * t; a[2][c] += p2 * t; a[3][c] += p3 * t;
      }
    }
    #pragma unroll
    for (int h = 0; h < HH; ++h){
      short4v pk;
      #pragma unroll
      for (int c = 0; c < 4; ++c) pk[c] = f2bf(a[h][c]);
      *(short4v*)(p_y + ((size_t)h * BSN + n) * EE + e) = pk;
    }
  }
}

// ---------------------------------------------------------------------------
// 64x64-tile bf16 MFMA GEMM, C = A @ Bt^T with fused epilogue.
// A: [M][Kdim] bf16 row-major. Bt: [N][Kdim] bf16 (i.e. B transposed).
// MODE 0: cat[m][768*z + f] = bf16( gelu(x[m][f] + acc + addv[768z+f]) )
// MODE 1: out[m][f]         = x[m][f] + gelu(acc + addv[f])
// grid (M/64, N/64, Z)
// ---------------------------------------------------------------------------
template<int MODE>
__global__ __launch_bounds__(256) void k_gemm(const short* __restrict__ A,
                                              const short* __restrict__ Bt,
                                              const float* __restrict__ addv,
                                              const float* __restrict__ x,
                                              void* __restrict__ out,
                                              int Kdim, size_t strideA, size_t strideB){
  __shared__ short As[64][72];
  __shared__ short Bs[64][72];
  const int z = blockIdx.z;
  const short* Ah = A + strideA * z;
  const short* Bh = Bt + strideB * z;
  const float* addh = addv + (size_t)768 * z;

  const int tid = threadIdx.x;
  const int wave = tid >> 6, lane = tid & 63;
  const int quad = lane >> 4, l16 = lane & 15;
  const int m0 = blockIdx.x * 64, n0 = blockIdx.y * 64;
  const int r = tid >> 3, c8 = (tid & 7) * 8;

  float4v acc[4];
  #pragma unroll
  for (int t = 0; t < 4; ++t) acc[t] = (float4v){0.f, 0.f, 0.f, 0.f};

  const short* Ap0 = Ah + (size_t)(m0 + r) * Kdim + c8;
  const short* Ap1 = Ah + (size_t)(m0 + r + 32) * Kdim + c8;
  const short* Bp0 = Bh + (size_t)(n0 + r) * Kdim + c8;
  const short* Bp1 = Bh + (size_t)(n0 + r + 32) * Kdim + c8;

  for (int k0 = 0; k0 < Kdim; k0 += 64){
    short8 a0 = *(const short8*)(Ap0 + k0);
    short8 a1 = *(const short8*)(Ap1 + k0);
    short8 b0 = *(const short8*)(Bp0 + k0);
    short8 b1 = *(const short8*)(Bp1 + k0);
    __syncthreads();
    *(short8*)(&As[r][c8])      = a0;
    *(short8*)(&As[r + 32][c8]) = a1;
    *(short8*)(&Bs[r][c8])      = b0;
    *(short8*)(&Bs[r + 32][c8]) = b1;
    __syncthreads();
    #pragma unroll
    for (int kk = 0; kk < 64; kk += 32){
      short8 bf = *(const short8*)(&Bs[16 * wave + l16][kk + quad * 8]);
      #pragma unroll
      for (int t = 0; t < 4; ++t){
        short8 af = *(const short8*)(&As[16 * t + l16][kk + quad * 8]);
        acc[t] = __builtin_amdgcn_mfma_f32_16x16x32_bf16(af, bf, acc[t], 0, 0, 0);
      }
    }
  }

  const int f = n0 + 16 * wave + l16;       // local col in [0,768)
  const float add = addh[f];
  #pragma unroll
  for (int t = 0; t < 4; ++t){
    #pragma unroll
    for (int rr = 0; rr < 4; ++rr){
      const int m = m0 + 16 * t + quad * 4 + rr;
      const float val = acc[t][rr] + add;
      const float xf = x[(size_t)m * EE + f];
      if (MODE == 0){
        ((short*)out)[(size_t)m * (HH * EE) + 768 * z + f] = f2bf(gelu_tanh(xf + val));
      } else {
        ((float*)out)[(size_t)m * EE + f] = xf + gelu_tanh(val);
      }
    }
  }
}

// ---------------------------------------------------------------------------
extern "C" void kernel_launch(void* const* d_in, const int* in_sizes, int n_in,
                              void* d_out, int out_size, void* d_ws, size_t ws_size,
                              hipStream_t stream){
  const float* x    = (const float*)d_in[0];
  const float* y    = (const float*)d_in[1];
  const float* g    = (const float*)d_in[2];
  const float* beta = (const float*)d_in[3];
  const float* W1   = (const float*)d_in[4];
  const float* b1   = (const float*)d_in[5];
  const float* W2y  = (const float*)d_in[7];   // W2x, b2 cancel in softmax
  const float* Wm   = (const float*)d_in[9];
  const float* bm   = (const float*)d_in[10];

  char* ws = (char*)d_ws;
  float* v    = (float*)(ws + 0);              // 4*768 f32
  float* b1p  = (float*)(ws + 12288);          // 4*768 f32
  short* W1t  = (short*)(ws + 24576);          // 4*768*768 bf16 (transposed)
  short* Wmt  = (short*)(ws + 4743168);        // 768*3072 bf16 (transposed)
  short* p_y  = (short*)(ws + 9461760);        // 4*2048*768 bf16
  short* catb = (short*)(ws + 22044672);       // 2048*3072 bf16
  float* out  = (float*)d_out;

  k_v<<<dim3(768), dim3(256), 0, stream>>>(W1, W2y, g, b1, v, b1p);
  k_b1p_acc<<<dim3(256), dim3(256), 0, stream>>>(W1, beta, b1p);
  k_tW1<<<dim3(24, 24, 4), dim3(256), 0, stream>>>(W1, g, W1t);
  k_tWm<<<dim3(96, 24), dim3(256), 0, stream>>>(Wm, Wmt);
  k_pass_y<<<dim3(2048), dim3(256), 0, stream>>>(y, v, p_y);
  k_gemm<0><<<dim3(32, 12, 4), dim3(256), 0, stream>>>(
      p_y, W1t, b1p, x, (void*)catb, 768, (size_t)2048 * 768, (size_t)768 * 768);
  k_gemm<1><<<dim3(32, 12, 1), dim3(256), 0, stream>>>(
      catb, Wmt, bm, x, (void*)out, 3072, (size_t)0, (size_t)0);
}

// Round 3
// 444.024 us; speedup vs baseline: 1.0234x; 1.0004x over previous
//
#include <hip/hip_runtime.h>
#include <hip/hip_bf16.h>
#include <math.h>

#define EE 768
#define HH 4
#define KK 36
#define BSN 2048

typedef __attribute__((ext_vector_type(8))) short short8;
typedef __attribute__((ext_vector_type(4))) short short4v;
typedef __attribute__((ext_vector_type(4))) float float4v;

__device__ inline short f2bf(float x){
  return __builtin_bit_cast(short, __float2bfloat16(x));
}
__device__ inline float bf2f(short s){
  return __bfloat162float(__builtin_bit_cast(__hip_bfloat16, s));
}
__device__ inline float gelu_tanh(float x){
  // jax.nn.gelu default (approximate=True)
  float t = tanhf(0.79788456080286536f * (x + 0.044715f * x * x * x));
  return 0.5f * x * (1.0f + t);
}

// ---------------------------------------------------------------------------
// v[h][e] = g[h][e] * sum_f W1[h][e][f] * W2y[h][f]    (one wave per (h,e))
// also initializes b1p = b1 (first 12 blocks' worth of threads)
// ---------------------------------------------------------------------------
__global__ __launch_bounds__(256) void k_v(const float* __restrict__ W1,
                                           const float* __restrict__ W2y,
                                           const float* __restrict__ g,
                                           const float* __restrict__ b1,
                                           float* __restrict__ v,
                                           float* __restrict__ b1p){
  const int wid  = blockIdx.x * 4 + (threadIdx.x >> 6);
  const int lane = threadIdx.x & 63;
  const int h = wid / EE, e = wid % EE;
  const float* W  = W1 + ((size_t)h * EE + e) * EE;
  const float* wy = W2y + h * EE;
  float acc = 0.f;
  #pragma unroll
  for (int j = 0; j < 12; ++j){
    int f = lane + 64 * j;
    acc += W[f] * wy[f];
  }
  #pragma unroll
  for (int off = 32; off; off >>= 1) acc += __shfl_xor(acc, off);
  if (lane == 0) v[h * EE + e] = g[h * EE + e] * acc;

  int idx = blockIdx.x * 256 + threadIdx.x;
  if (idx < HH * EE) b1p[idx] = b1[idx];
}

// ---------------------------------------------------------------------------
// b1p[h][f] += sum_e beta[h][e] * W1[h][e][f]   (partial e-chunks + atomics)
// grid: 256 blocks = 4 h * 64 e-chunks of 12
// ---------------------------------------------------------------------------
__global__ __launch_bounds__(256) void k_b1p_acc(const float* __restrict__ W1,
                                                 const float* __restrict__ beta,
                                                 float* __restrict__ b1p){
  const int h   = blockIdx.x >> 6;
  const int ec0 = (blockIdx.x & 63) * 12;
  const float* W  = W1 + (size_t)h * EE * EE;
  const float* bt = beta + h * EE;
  const int f = threadIdx.x;
  float a0 = 0.f, a1 = 0.f, a2 = 0.f;
  #pragma unroll
  for (int e = ec0; e < ec0 + 12; ++e){
    float be = bt[e];
    const float* row = W + (size_t)e * EE;
    a0 += be * row[f];
    a1 += be * row[f + 256];
    a2 += be * row[f + 512];
  }
  atomicAdd(&b1p[h * EE + f],       a0);
  atomicAdd(&b1p[h * EE + f + 256], a1);
  atomicAdd(&b1p[h * EE + f + 512], a2);
}

// ---------------------------------------------------------------------------
// W1t[h][f][e] = bf16( g[h][e] * W1[h][e][f] )   (transposed, bf16)
// grid (24 e-tiles, 24 f-tiles, 4 h), 256 threads
// ---------------------------------------------------------------------------
__global__ __launch_bounds__(256) void k_tW1(const float* __restrict__ W1,
                                             const float* __restrict__ g,
                                             short* __restrict__ W1t){
  __shared__ float tile[32][33];
  const int h  = blockIdx.z;
  const int e0 = blockIdx.x * 32, f0 = blockIdx.y * 32;
  const int tx = threadIdx.x & 31, ty = threadIdx.x >> 5;
  const float* W = W1 + (size_t)h * EE * EE;
  #pragma unroll
  for (int i = 0; i < 4; ++i){
    int e = e0 + ty + 8 * i;
    tile[ty + 8 * i][tx] = W[(size_t)e * EE + f0 + tx] * g[h * EE + e];
  }
  __syncthreads();
  #pragma unroll
  for (int i = 0; i < 4; ++i){
    int f = f0 + ty + 8 * i;
    W1t[((size_t)h * EE + f) * EE + e0 + tx] = f2bf(tile[tx][ty + 8 * i]);
  }
}

// ---------------------------------------------------------------------------
// Wmt[f][c] = bf16( Wm[c][f] )   c in [0,3072), f in [0,768)
// grid (96 c-tiles, 24 f-tiles)
// ---------------------------------------------------------------------------
__global__ __launch_bounds__(256) void k_tWm(const float* __restrict__ Wm,
                                             short* __restrict__ Wmt){
  __shared__ float tile[32][33];
  const int c0 = blockIdx.x * 32, f0 = blockIdx.y * 32;
  const int tx = threadIdx.x & 31, ty = threadIdx.x >> 5;
  #pragma unroll
  for (int i = 0; i < 4; ++i){
    tile[ty + 8 * i][tx] = Wm[(size_t)(c0 + ty + 8 * i) * EE + f0 + tx];
  }
  __syncthreads();
  #pragma unroll
  for (int i = 0; i < 4; ++i){
    Wmt[(size_t)(f0 + ty + 8 * i) * (HH * EE) + c0 + tx] = f2bf(tile[tx][ty + 8 * i]);
  }
}

// ---------------------------------------------------------------------------
// Flash-style fused y pass: ONE WAVE PER ROW n. For each k-row: LN0 ->
// logits d_h = yn . v_h (x_/W2x/b2 cancel in softmax) -> online softmax
// (running m,l per head, wave-uniform rescale branch) -> acc_h += w * yn.
// No LDS, no barriers; 2-row register prefetch keeps ~48 dwordx4/CU in
// flight. Exactly 2048 waves = 8 waves/CU, all resident.
// ---------------------------------------------------------------------------
__global__ __launch_bounds__(256) void k_pass_y(const float* __restrict__ y,
                                                const float* __restrict__ v,
                                                short* __restrict__ p_y){
  const int wave = threadIdx.x >> 6, lane = threadIdx.x & 63;
  const int n = blockIdx.x * 4 + wave;
  const float* base = y + (size_t)n * KK * EE + 4 * lane;

  float4v vreg[HH][3];
  #pragma unroll
  for (int h = 0; h < HH; ++h)
    #pragma unroll
    for (int j = 0; j < 3; ++j)
      vreg[h][j] = *(const float4v*)(v + h * EE + 4 * lane + 256 * j);

  float4v acc[HH][3];
  #pragma unroll
  for (int h = 0; h < HH; ++h)
    #pragma unroll
    for (int j = 0; j < 3; ++j)
      acc[h][j] = (float4v){0.f, 0.f, 0.f, 0.f};
  float m[HH], l[HH];
  #pragma unroll
  for (int h = 0; h < HH; ++h){ m[h] = -INFINITY; l[h] = 0.f; }

  // 2-deep register prefetch pipeline
  float4v bufA[3], bufB[3];
  #pragma unroll
  for (int j = 0; j < 3; ++j) bufA[j] = *(const float4v*)(base + 256 * j);
  #pragma unroll
  for (int j = 0; j < 3; ++j) bufB[j] = *(const float4v*)(base + EE + 256 * j);

  #pragma unroll 2
  for (int k = 0; k < KK; ++k){
    float4v cur[3];
    #pragma unroll
    for (int j = 0; j < 3; ++j) cur[j] = bufA[j];
    #pragma unroll
    for (int j = 0; j < 3; ++j) bufA[j] = bufB[j];
    if (k + 2 < KK){
      const float* rp = base + (size_t)(k + 2) * EE;
      #pragma unroll
      for (int j = 0; j < 3; ++j) bufB[j] = *(const float4v*)(rp + 256 * j);
    }

    // LN statistics
    float s = 0.f, s2 = 0.f;
    #pragma unroll
    for (int j = 0; j < 3; ++j)
      #pragma unroll
      for (int c = 0; c < 4; ++c){ float t = cur[j][c]; s += t; s2 += t * t; }
    #pragma unroll
    for (int off = 32; off; off >>= 1){
      s  += __shfl_xor(s, off);
      s2 += __shfl_xor(s2, off);
    }
    const float mu = s * (1.f / EE);
    const float rs = rsqrtf(s2 * (1.f / EE) - mu * mu + 1e-5f);

    // normalize in place + head logits
    float d[HH] = {0.f, 0.f, 0.f, 0.f};
    #pragma unroll
    for (int j = 0; j < 3; ++j)
      #pragma unroll
      for (int c = 0; c < 4; ++c){
        float t = (cur[j][c] - mu) * rs;
        cur[j][c] = t;
        d[0] += t * vreg[0][j][c];
        d[1] += t * vreg[1][j][c];
        d[2] += t * vreg[2][j][c];
        d[3] += t * vreg[3][j][c];
      }
    #pragma unroll
    for (int off = 32; off; off >>= 1){
      d[0] += __shfl_xor(d[0], off);
      d[1] += __shfl_xor(d[1], off);
      d[2] += __shfl_xor(d[2], off);
      d[3] += __shfl_xor(d[3], off);
    }

    // online softmax accumulate (d[h], m[h] are wave-uniform -> uniform branch)
    #pragma unroll
    for (int h = 0; h < HH; ++h){
      if (d[h] > m[h]){
        float sc = __expf(m[h] - d[h]);   // first iter: exp(-inf)=0
        l[h] *= sc;
        #pragma unroll
        for (int j = 0; j < 3; ++j)
          #pragma unroll
          for (int c = 0; c < 4; ++c) acc[h][j][c] *= sc;
        m[h] = d[h];
      }
      float w = __expf(d[h] - m[h]);
      l[h] += w;
      #pragma unroll
      for (int j = 0; j < 3; ++j)
        #pragma unroll
        for (int c = 0; c < 4; ++c) acc[h][j][c] += w * cur[j][c];
    }
  }

  // finalize: p_y[h][n][e] = acc/l  (bf16)
  #pragma unroll
  for (int h = 0; h < HH; ++h){
    const float inv = 1.f / l[h];
    #pragma unroll
    for (int j = 0; j < 3; ++j){
      short4v pk;
      #pragma unroll
      for (int c = 0; c < 4; ++c) pk[c] = f2bf(acc[h][j][c] * inv);
      *(short4v*)(p_y + ((size_t)h * BSN + n) * EE + 4 * lane + 256 * j) = pk;
    }
  }
}

// ---------------------------------------------------------------------------
// 64x64-tile bf16 MFMA GEMM, C = A @ Bt^T with fused epilogue.
// A: [M][Kdim] bf16 row-major. Bt: [N][Kdim] bf16 (i.e. B transposed).
// MODE 0: cat[m][768*z + f] = bf16( gelu(x[m][f] + acc + addv[768z+f]) )
// MODE 1: out[m][f]         = x[m][f] + gelu(acc + addv[f])
// grid (M/64, N/64, Z)
// ---------------------------------------------------------------------------
template<int MODE>
__global__ __launch_bounds__(256) void k_gemm(const short* __restrict__ A,
                                              const short* __restrict__ Bt,
                                              const float* __restrict__ addv,
                                              const float* __restrict__ x,
                                              void* __restrict__ out,
                                              int Kdim, size_t strideA, size_t strideB){
  __shared__ short As[64][72];
  __shared__ short Bs[64][72];
  const int z = blockIdx.z;
  const short* Ah = A + strideA * z;
  const short* Bh = Bt + strideB * z;
  const float* addh = addv + (size_t)768 * z;

  const int tid = threadIdx.x;
  const int wave = tid >> 6, lane = tid & 63;
  const int quad = lane >> 4, l16 = lane & 15;
  const int m0 = blockIdx.x * 64, n0 = blockIdx.y * 64;
  const int r = tid >> 3, c8 = (tid & 7) * 8;

  float4v acc[4];
  #pragma unroll
  for (int t = 0; t < 4; ++t) acc[t] = (float4v){0.f, 0.f, 0.f, 0.f};

  const short* Ap0 = Ah + (size_t)(m0 + r) * Kdim + c8;
  const short* Ap1 = Ah + (size_t)(m0 + r + 32) * Kdim + c8;
  const short* Bp0 = Bh + (size_t)(n0 + r) * Kdim + c8;
  const short* Bp1 = Bh + (size_t)(n0 + r + 32) * Kdim + c8;

  for (int k0 = 0; k0 < Kdim; k0 += 64){
    short8 a0 = *(const short8*)(Ap0 + k0);
    short8 a1 = *(const short8*)(Ap1 + k0);
    short8 b0 = *(const short8*)(Bp0 + k0);
    short8 b1 = *(const short8*)(Bp1 + k0);
    __syncthreads();
    *(short8*)(&As[r][c8])      = a0;
    *(short8*)(&As[r + 32][c8]) = a1;
    *(short8*)(&Bs[r][c8])      = b0;
    *(short8*)(&Bs[r + 32][c8]) = b1;
    __syncthreads();
    #pragma unroll
    for (int kk = 0; kk < 64; kk += 32){
      short8 bf = *(const short8*)(&Bs[16 * wave + l16][kk + quad * 8]);
      #pragma unroll
      for (int t = 0; t < 4; ++t){
        short8 af = *(const short8*)(&As[16 * t + l16][kk + quad * 8]);
        acc[t] = __builtin_amdgcn_mfma_f32_16x16x32_bf16(af, bf, acc[t], 0, 0, 0);
      }
    }
  }

  const int f = n0 + 16 * wave + l16;       // local col in [0,768)
  const float add = addh[f];
  #pragma unroll
  for (int t = 0; t < 4; ++t){
    #pragma unroll
    for (int rr = 0; rr < 4; ++rr){
      const int m = m0 + 16 * t + quad * 4 + rr;
      const float val = acc[t][rr] + add;
      const float xf = x[(size_t)m * EE + f];
      if (MODE == 0){
        ((short*)out)[(size_t)m * (HH * EE) + 768 * z + f] = f2bf(gelu_tanh(xf + val));
      } else {
        ((float*)out)[(size_t)m * EE + f] = xf + gelu_tanh(val);
      }
    }
  }
}

// ---------------------------------------------------------------------------
extern "C" void kernel_launch(void* const* d_in, const int* in_sizes, int n_in,
                              void* d_out, int out_size, void* d_ws, size_t ws_size,
                              hipStream_t stream){
  const float* x    = (const float*)d_in[0];
  const float* y    = (const float*)d_in[1];
  const float* g    = (const float*)d_in[2];
  const float* beta = (const float*)d_in[3];
  const float* W1   = (const float*)d_in[4];
  const float* b1   = (const float*)d_in[5];
  const float* W2y  = (const float*)d_in[7];   // W2x, b2 cancel in softmax
  const float* Wm   = (const float*)d_in[9];
  const float* bm   = (const float*)d_in[10];

  char* ws = (char*)d_ws;
  float* v    = (float*)(ws + 0);              // 4*768 f32
  float* b1p  = (float*)(ws + 12288);          // 4*768 f32
  short* W1t  = (short*)(ws + 24576);          // 4*768*768 bf16 (transposed)
  short* Wmt  = (short*)(ws + 4743168);        // 768*3072 bf16 (transposed)
  short* p_y  = (short*)(ws + 9461760);        // 4*2048*768 bf16
  short* catb = (short*)(ws + 22044672);       // 2048*3072 bf16
  float* out  = (float*)d_out;

  k_v<<<dim3(768), dim3(256), 0, stream>>>(W1, W2y, g, b1, v, b1p);
  k_b1p_acc<<<dim3(256), dim3(256), 0, stream>>>(W1, beta, b1p);
  k_tW1<<<dim3(24, 24, 4), dim3(256), 0, stream>>>(W1, g, W1t);
  k_tWm<<<dim3(96, 24), dim3(256), 0, stream>>>(Wm, Wmt);
  k_pass_y<<<dim3(512), dim3(256), 0, stream>>>(y, v, p_y);
  k_gemm<0><<<dim3(32, 12, 4), dim3(256), 0, stream>>>(
      p_y, W1t, b1p, x, (void*)catb, 768, (size_t)2048 * 768, (size_t)768 * 768);
  k_gemm<1><<<dim3(32, 12, 1), dim3(256), 0, stream>>>(
      catb, Wmt, bm, x, (void*)out, 3072, (size_t)0, (size_t)0);
}